// Round 3
// baseline (214.489 us; speedup 1.0000x reference)
//
#include <hip/hip_runtime.h>

// Problem: z0 (2,512,128), z1 (2,512,128), W (64,256), out (2,64,512,512) f32
// y[n,h,x,y] = BN(ELU( sum_c Wd[h,c]|z0[n,x,c]-z1[n,y,c]| + Wm[h,c] z0*z1 + b[h] ))
#define LL 512
#define DDIM 128
#define HCH 64
#define NBLK0 2048  // conv grid: 2n * 64bx * 16by ; tile = 8x * 32y * 64h

typedef float f32x4 __attribute__((ext_vector_type(4)));
typedef __bf16 bf16x8 __attribute__((ext_vector_type(8)));

__device__ __forceinline__ float elu_f(float v) {
  return v > 0.0f ? v : (__expf(v) - 1.0f);
}

// Pre-convert W (64x256 f32) into MFMA A-fragment order, bf16.
// Slot s = (chunk ck 0..7, htile 0..3, lane 0..63): W[ht*16+(l&15)][ck*32+8*(l>>4)+j]
__global__ void wprep_kernel(const float* __restrict__ w, bf16x8* __restrict__ wf) {
  int s = blockIdx.x * 256 + threadIdx.x;  // 0..2047
  int ck = s >> 8;
  int rem = s & 255;
  int ht = rem >> 6;
  int l = rem & 63;
  int h = ht * 16 + (l & 15);
  int c = ck * 32 + ((l >> 4) << 3);
  const float* src = w + h * 256 + c;
  bf16x8 v;
#pragma unroll
  for (int j = 0; j < 8; ++j) v[j] = (__bf16)src[j];
  wf[s] = v;
}

// z1f LDS fragment-index swizzle (store/read must match): spreads staging writes
// across bank groups; XOR term is quarter-wave-uniform on read (conflict-free).
__device__ __forceinline__ int swz(int i) { return i ^ ((i >> 4) & 7); }

// Compute ELU(conv), store y as bf16 (natural layout), emit per-block BN partials.
__global__ __launch_bounds__(256, 2) void conv_stats_kernel(
    const float* __restrict__ z0g, const float* __restrict__ z1g,
    const bf16x8* __restrict__ wf, const float* __restrict__ cb,
    float* __restrict__ partials, __bf16* __restrict__ yb) {
  __shared__ float z0_lds[8 * 128];  // 4 KB row-major [x_local][c]
  __shared__ f32x4 z1f[1024];        // 16 KB; idx = ((p*2+yt)*4+ck)*64+fl, swizzled
  __shared__ float sred[128];
  __shared__ float cb_lds[64];

  const int t = threadIdx.x;
  const int lane = t & 63;
  const int wv = t >> 6;
  const int bid = blockIdx.x;
  const int by = bid & 15, bx = (bid >> 4) & 63, n = bid >> 10;
  const int x0 = bx * 8, y0 = by * 32;

  // ---- staging ----
  if (t < 128) {
    int r = t >> 4, cs = t & 15;  // z0: 8 rows x 16 segs
    const f32x4* g0 = (const f32x4*)(z0g + (size_t)(n * LL + x0 + r) * DDIM + cs * 8);
    ((f32x4*)z0_lds)[r * 32 + cs * 2 + 0] = g0[0];
    ((f32x4*)z0_lds)[r * 32 + cs * 2 + 1] = g0[1];
  }
#pragma unroll
  for (int s = t; s < 512; s += 256) {  // z1: 32 rows x 16 segs
    int rr = s >> 4, cs1 = s & 15;
    const f32x4* g1 = (const f32x4*)(z1g + (size_t)(n * LL + y0 + rr) * DDIM + cs1 * 8);
    f32x4 b0 = g1[0], b1 = g1[1];
    int yt = rr >> 4, rl = rr & 15, ck = cs1 >> 2, gg = cs1 & 3, fl = gg * 16 + rl;
    z1f[swz(((0 * 2 + yt) * 4 + ck) * 64 + fl)] = b0;
    z1f[swz(((1 * 2 + yt) * 4 + ck) * 64 + fl)] = b1;
  }
  if (t < 128) sred[t] = 0.0f;
  if (t < 64) cb_lds[t] = cb[t];
  __syncthreads();

  f32x4 acc[2][4][2];  // [xi][htile][yt]
  const f32x4 zero4 = {0.f, 0.f, 0.f, 0.f};
#pragma unroll
  for (int xi = 0; xi < 2; ++xi)
#pragma unroll
    for (int ht = 0; ht < 4; ++ht)
#pragma unroll
      for (int yt = 0; yt < 2; ++yt) acc[xi][ht][yt] = zero4;

  // ---- main loop: 4 z-chunks; each feeds dif (ck) and mul (ck+4) MFMAs ----
#pragma unroll
  for (int ckz = 0; ckz < 4; ++ckz) {
    bf16x8 afd[4], afm[4];
#pragma unroll
    for (int ht = 0; ht < 4; ++ht) {
      afd[ht] = wf[(ckz * 4 + ht) * 64 + lane];
      afm[ht] = wf[((ckz + 4) * 4 + ht) * 64 + lane];
    }
    f32x4 b0[2], b1[2];
#pragma unroll
    for (int yt = 0; yt < 2; ++yt) {
      b0[yt] = z1f[swz(((0 * 2 + yt) * 4 + ckz) * 64 + lane)];
      b1[yt] = z1f[swz(((1 * 2 + yt) * 4 + ckz) * 64 + lane)];
    }
#pragma unroll
    for (int xi = 0; xi < 2; ++xi) {
      const int xl = wv * 2 + xi;
      const f32x4* z0p = (const f32x4*)&z0_lds[xl * 128 + ckz * 32 + ((lane >> 4) << 3)];
      f32x4 a0 = z0p[0], a1 = z0p[1];
#pragma unroll
      for (int yt = 0; yt < 2; ++yt) {
        bf16x8 bd, bm;
#pragma unroll
        for (int j = 0; j < 4; ++j) {
          bd[j] = (__bf16)fabsf(a0[j] - b0[yt][j]);
          bd[4 + j] = (__bf16)fabsf(a1[j] - b1[yt][j]);
          bm[j] = (__bf16)(a0[j] * b0[yt][j]);
          bm[4 + j] = (__bf16)(a1[j] * b1[yt][j]);
        }
#pragma unroll
        for (int ht = 0; ht < 4; ++ht) {
          acc[xi][ht][yt] =
              __builtin_amdgcn_mfma_f32_16x16x32_bf16(afd[ht], bd, acc[xi][ht][yt], 0, 0, 0);
          acc[xi][ht][yt] =
              __builtin_amdgcn_mfma_f32_16x16x32_bf16(afm[ht], bm, acc[xi][ht][yt], 0, 0, 0);
        }
      }
    }
  }

  // ---- epilogue: ELU, bf16 store, stats ----
  float s1[4][4], s2[4][4];
#pragma unroll
  for (int ht = 0; ht < 4; ++ht)
#pragma unroll
    for (int i = 0; i < 4; ++i) { s1[ht][i] = 0.f; s2[ht][i] = 0.f; }
#pragma unroll
  for (int xi = 0; xi < 2; ++xi) {
    const int x = x0 + wv * 2 + xi;
#pragma unroll
    for (int ht = 0; ht < 4; ++ht)
#pragma unroll
      for (int i = 0; i < 4; ++i) {
        int h = ht * 16 + ((lane >> 4) << 2) + i;
        float v0 = elu_f(acc[xi][ht][0][i] + cb_lds[h]);
        float v1 = elu_f(acc[xi][ht][1][i] + cb_lds[h]);
        s1[ht][i] += v0 + v1;
        s2[ht][i] += v0 * v0 + v1 * v1;
        // yt halves are adjacent 32B quarter-wave segments of one 64B sector ->
        // L2 write-combines; no RMW.
        __bf16* p = yb + ((size_t)(n * HCH + h) * LL + x) * LL + y0 + (lane & 15);
        p[0] = (__bf16)v0;
        p[16] = (__bf16)v1;
      }
  }
#pragma unroll
  for (int ht = 0; ht < 4; ++ht)
#pragma unroll
    for (int i = 0; i < 4; ++i) {
#pragma unroll
      for (int m = 1; m <= 8; m <<= 1) {
        s1[ht][i] += __shfl_xor(s1[ht][i], m, 64);
        s2[ht][i] += __shfl_xor(s2[ht][i], m, 64);
      }
      if ((lane & 15) == 0) {
        int h = ht * 16 + ((lane >> 4) << 2) + i;
        atomicAdd(&sred[h], s1[ht][i]);
        atomicAdd(&sred[64 + h], s2[ht][i]);
      }
    }
  __syncthreads();
  if (t < 128) partials[(size_t)bid * 128 + t] = sred[t];
}

__global__ void bn_finalize_kernel(const float* __restrict__ partials,
                                   const float* __restrict__ gamma,
                                   const float* __restrict__ beta,
                                   float* __restrict__ sstab) {
  const int h = blockIdx.x, t = threadIdx.x;
  const int lane = t & 63, wv = t >> 6;
  float s1 = 0.f, s2 = 0.f;
  for (int b = t; b < NBLK0; b += 256) {
    s1 += partials[(size_t)b * 128 + h];
    s2 += partials[(size_t)b * 128 + 64 + h];
  }
#pragma unroll
  for (int m = 1; m <= 32; m <<= 1) {
    s1 += __shfl_xor(s1, m, 64);
    s2 += __shfl_xor(s2, m, 64);
  }
  __shared__ float r1[4], r2[4];
  if (lane == 0) { r1[wv] = s1; r2[wv] = s2; }
  __syncthreads();
  if (t == 0) {
    float S1 = r1[0] + r1[1] + r1[2] + r1[3];
    float S2 = r2[0] + r2[1] + r2[2] + r2[3];
    const float M = 524288.0f;  // 2 * 512 * 512 per channel
    float mean = S1 / M;
    float var = S2 / M - mean * mean;
    var = var < 0.f ? 0.f : var;
    float sc = gamma[h] * rsqrtf(var + 1e-5f);
    sstab[h] = sc;
    sstab[64 + h] = beta[h] - mean * sc;
  }
}

// Streaming normalize: bf16 y -> f32 out with per-channel affine.
__global__ __launch_bounds__(256) void bn_apply_kernel(const __bf16* __restrict__ yb,
                                                       const float* __restrict__ sstab,
                                                       float* __restrict__ out) {
  const int tid = blockIdx.x * 256 + threadIdx.x;  // 0..524287
#pragma unroll
  for (int g = 0; g < 8; ++g) {
    int ch = tid + (g << 19);          // bf16x8 chunk id, 0..4194303
    int h = (ch >> 15) & 63;           // 32768 chunks per channel (wave-uniform)
    float sc = sstab[h], sh = sstab[64 + h];
    bf16x8 v = ((const bf16x8*)yb)[ch];
    f32x4 o0, o1;
#pragma unroll
    for (int j = 0; j < 4; ++j) {
      o0[j] = (float)v[j] * sc + sh;
      o1[j] = (float)v[4 + j] * sc + sh;
    }
    ((f32x4*)out)[ch * 2 + 0] = o0;
    ((f32x4*)out)[ch * 2 + 1] = o1;
  }
}

extern "C" void kernel_launch(void* const* d_in, const int* in_sizes, int n_in,
                              void* d_out, int out_size, void* d_ws, size_t ws_size,
                              hipStream_t stream) {
  (void)in_sizes; (void)n_in; (void)out_size; (void)ws_size;
  const float* z0 = (const float*)d_in[0];
  const float* z1 = (const float*)d_in[1];
  const float* w = (const float*)d_in[2];
  const float* cb = (const float*)d_in[3];
  const float* gamma = (const float*)d_in[4];
  const float* beta = (const float*)d_in[5];
  float* out = (float*)d_out;

  char* ws = (char*)d_ws;
  bf16x8* wf = (bf16x8*)ws;                          // 32 KB
  float* partials = (float*)(ws + (32 << 10));       // 2048 * 128 * 4 = 1 MB
  float* sstab = (float*)(ws + (32 << 10) + (1 << 20));
  __bf16* yb = (__bf16*)(ws + (32 << 10) + (1 << 20) + (4 << 10));  // 64 MB

  wprep_kernel<<<8, 256, 0, stream>>>(w, wf);
  conv_stats_kernel<<<NBLK0, 256, 0, stream>>>(z0, z1, wf, cb, partials, yb);
  bn_finalize_kernel<<<64, 256, 0, stream>>>(partials, gamma, beta, sstab);
  bn_apply_kernel<<<2048, 256, 0, stream>>>(yb, sstab, out);
}

// Round 4
// 212.747 us; speedup vs baseline: 1.0082x; 1.0082x over previous
//
#include <hip/hip_runtime.h>

// Problem: z0 (2,512,128), z1 (2,512,128), W (64,256), out (2,64,512,512) f32
// y[n,h,x,y] = BN(ELU( sum_c Wd[h,c]|z0[n,x,c]-z1[n,y,c]| + Wm[h,c] z0*z1 + b[h] ))
#define LL 512
#define DDIM 128
#define HCH 64
#define NBLK 4096  // conv grid: 2n * 128bx * 16by ; tile = 4x * 32y * 64h

typedef float f32x4 __attribute__((ext_vector_type(4)));
typedef __bf16 bf16x8 __attribute__((ext_vector_type(8)));

__device__ __forceinline__ float elu_f(float v) {
  return v > 0.0f ? v : (__expf(v) - 1.0f);
}

// Pre-convert W (64x256 f32) into MFMA A-fragment order, bf16.
// Slot s = (chunk ck 0..7, htile 0..3, lane 0..63): W[ht*16+(l&15)][ck*32+8*(l>>4)+j]
__global__ void wprep_kernel(const float* __restrict__ w, bf16x8* __restrict__ wf) {
  int s = blockIdx.x * 256 + threadIdx.x;  // 0..2047
  int ck = s >> 8;
  int rem = s & 255;
  int ht = rem >> 6;
  int l = rem & 63;
  int h = ht * 16 + (l & 15);
  int c = ck * 32 + ((l >> 4) << 3);
  const float* src = w + h * 256 + c;
  bf16x8 v;
#pragma unroll
  for (int j = 0; j < 8; ++j) v[j] = (__bf16)src[j];
  wf[s] = v;
}

// z1f LDS fragment-index swizzle (store/read must match): spreads staging writes
// across bank groups; XOR term is quarter-wave-uniform on read (conflict-free).
__device__ __forceinline__ int swz(int i) { return i ^ ((i >> 4) & 7); }

// PASS 0: conv + ELU -> per-block per-channel sum/sumsq partials only.
// PASS 1: recompute conv + ELU, apply BN affine, write output.
// Tile 4x*32y*64h, one x per wave; acc = 32 AGPR -> total regs <= 128 -> 4 waves/SIMD.
template <int PASS>
__global__ __launch_bounds__(256, 4) void fused_kernel(
    const float* __restrict__ z0g, const float* __restrict__ z1g,
    const bf16x8* __restrict__ wf, const float* __restrict__ cb,
    const float* __restrict__ sstab, float* __restrict__ partials,
    float* __restrict__ out) {
  __shared__ float z0_lds[4 * 128];  // 2 KB row-major [x_local][c]
  __shared__ f32x4 z1f[1024];        // 16 KB; idx = ((p*2+yt)*4+ck)*64+fl, swizzled
  __shared__ float sred[128];
  __shared__ float cb_lds[64];
  __shared__ float sc_lds[128];

  const int t = threadIdx.x;
  const int lane = t & 63;
  const int wv = t >> 6;
  const int bid = blockIdx.x;
  const int by = bid & 15, bx = (bid >> 4) & 127, n = bid >> 11;
  const int x0 = bx * 4, y0 = by * 32;

  // ---- staging ----
  if (t < 128) {
    int r = t >> 5, cs = t & 31;  // z0: 4 rows x 32 f32x4 segs
    const f32x4* g0 = (const f32x4*)(z0g + (size_t)(n * LL + x0 + r) * DDIM + cs * 4);
    ((f32x4*)z0_lds)[r * 32 + cs] = g0[0];
  }
#pragma unroll
  for (int s = t; s < 512; s += 256) {  // z1: 32 rows x 16 8-float segs
    int rr = s >> 4, cs1 = s & 15;
    const f32x4* g1 = (const f32x4*)(z1g + (size_t)(n * LL + y0 + rr) * DDIM + cs1 * 8);
    f32x4 b0 = g1[0], b1 = g1[1];
    int yt = rr >> 4, rl = rr & 15, ck = cs1 >> 2, gg = cs1 & 3, fl = gg * 16 + rl;
    z1f[swz(((0 * 2 + yt) * 4 + ck) * 64 + fl)] = b0;
    z1f[swz(((1 * 2 + yt) * 4 + ck) * 64 + fl)] = b1;
  }
  if (t < 128) sred[t] = 0.0f;
  if (t < 64) cb_lds[t] = cb[t];
  if (PASS == 1 && t < 128) sc_lds[t] = sstab[t];
  __syncthreads();

  f32x4 acc[4][2];  // [htile][yt]
  const f32x4 zero4 = {0.f, 0.f, 0.f, 0.f};
#pragma unroll
  for (int ht = 0; ht < 4; ++ht)
#pragma unroll
    for (int yt = 0; yt < 2; ++yt) acc[ht][yt] = zero4;

  const int xl = wv;  // one x per wave

  // ---- main loop: 4 z-chunks; each feeds dif (ck) and mul (ck+4) MFMAs ----
#pragma unroll
  for (int ckz = 0; ckz < 4; ++ckz) {
    bf16x8 afd[4], afm[4];
#pragma unroll
    for (int ht = 0; ht < 4; ++ht) {
      afd[ht] = wf[(ckz * 4 + ht) * 64 + lane];
      afm[ht] = wf[((ckz + 4) * 4 + ht) * 64 + lane];
    }
    f32x4 b0[2], b1[2];
#pragma unroll
    for (int yt = 0; yt < 2; ++yt) {
      b0[yt] = z1f[swz(((0 * 2 + yt) * 4 + ckz) * 64 + lane)];
      b1[yt] = z1f[swz(((1 * 2 + yt) * 4 + ckz) * 64 + lane)];
    }
    const f32x4* z0p = (const f32x4*)&z0_lds[xl * 128 + ckz * 32 + ((lane >> 4) << 3)];
    f32x4 a0 = z0p[0], a1 = z0p[1];
#pragma unroll
    for (int yt = 0; yt < 2; ++yt) {
      bf16x8 bd, bm;
#pragma unroll
      for (int j = 0; j < 4; ++j) {
        bd[j] = (__bf16)fabsf(a0[j] - b0[yt][j]);
        bd[4 + j] = (__bf16)fabsf(a1[j] - b1[yt][j]);
        bm[j] = (__bf16)(a0[j] * b0[yt][j]);
        bm[4 + j] = (__bf16)(a1[j] * b1[yt][j]);
      }
#pragma unroll
      for (int ht = 0; ht < 4; ++ht) {
        acc[ht][yt] =
            __builtin_amdgcn_mfma_f32_16x16x32_bf16(afd[ht], bd, acc[ht][yt], 0, 0, 0);
        acc[ht][yt] =
            __builtin_amdgcn_mfma_f32_16x16x32_bf16(afm[ht], bm, acc[ht][yt], 0, 0, 0);
      }
    }
  }

  // ---- epilogue ----
  if (PASS == 0) {
    float s1[4][4], s2[4][4];
#pragma unroll
    for (int ht = 0; ht < 4; ++ht)
#pragma unroll
      for (int i = 0; i < 4; ++i) {
        int h = ht * 16 + ((lane >> 4) << 2) + i;
        float v0 = elu_f(acc[ht][0][i] + cb_lds[h]);
        float v1 = elu_f(acc[ht][1][i] + cb_lds[h]);
        s1[ht][i] = v0 + v1;
        s2[ht][i] = v0 * v0 + v1 * v1;
      }
#pragma unroll
    for (int ht = 0; ht < 4; ++ht)
#pragma unroll
      for (int i = 0; i < 4; ++i) {
#pragma unroll
        for (int m = 1; m <= 8; m <<= 1) {
          s1[ht][i] += __shfl_xor(s1[ht][i], m, 64);
          s2[ht][i] += __shfl_xor(s2[ht][i], m, 64);
        }
        if ((lane & 15) == 0) {
          int h = ht * 16 + ((lane >> 4) << 2) + i;
          atomicAdd(&sred[h], s1[ht][i]);
          atomicAdd(&sred[64 + h], s2[ht][i]);
        }
      }
    __syncthreads();
    if (t < 128) partials[(size_t)bid * 128 + t] = sred[t];
  } else {
    const int x = x0 + wv;
#pragma unroll
    for (int ht = 0; ht < 4; ++ht)
#pragma unroll
      for (int i = 0; i < 4; ++i) {
        int h = ht * 16 + ((lane >> 4) << 2) + i;
        float sc = sc_lds[h], sh = sc_lds[64 + h];
        float* p = out + ((size_t)(n * HCH + h) * LL + x) * LL + y0 + (lane & 15);
        // yt halves are the two 64B sectors of one 128B line, same wave,
        // back-to-back -> L2 write-combines, no RMW.
        float v0 = elu_f(acc[ht][0][i] + cb_lds[h]);
        float v1 = elu_f(acc[ht][1][i] + cb_lds[h]);
        p[0] = v0 * sc + sh;
        p[16] = v1 * sc + sh;
      }
  }
}

__global__ void bn_finalize_kernel(const float* __restrict__ partials,
                                   const float* __restrict__ gamma,
                                   const float* __restrict__ beta,
                                   float* __restrict__ sstab) {
  const int h = blockIdx.x, t = threadIdx.x;
  const int lane = t & 63, wv = t >> 6;
  float s1 = 0.f, s2 = 0.f;
  for (int b = t; b < NBLK; b += 256) {
    s1 += partials[(size_t)b * 128 + h];
    s2 += partials[(size_t)b * 128 + 64 + h];
  }
#pragma unroll
  for (int m = 1; m <= 32; m <<= 1) {
    s1 += __shfl_xor(s1, m, 64);
    s2 += __shfl_xor(s2, m, 64);
  }
  __shared__ float r1[4], r2[4];
  if (lane == 0) { r1[wv] = s1; r2[wv] = s2; }
  __syncthreads();
  if (t == 0) {
    float S1 = r1[0] + r1[1] + r1[2] + r1[3];
    float S2 = r2[0] + r2[1] + r2[2] + r2[3];
    const float M = 524288.0f;  // 2 * 512 * 512 per channel
    float mean = S1 / M;
    float var = S2 / M - mean * mean;
    var = var < 0.f ? 0.f : var;
    float sc = gamma[h] * rsqrtf(var + 1e-5f);
    sstab[h] = sc;
    sstab[64 + h] = beta[h] - mean * sc;
  }
}

extern "C" void kernel_launch(void* const* d_in, const int* in_sizes, int n_in,
                              void* d_out, int out_size, void* d_ws, size_t ws_size,
                              hipStream_t stream) {
  (void)in_sizes; (void)n_in; (void)out_size; (void)ws_size;
  const float* z0 = (const float*)d_in[0];
  const float* z1 = (const float*)d_in[1];
  const float* w = (const float*)d_in[2];
  const float* cb = (const float*)d_in[3];
  const float* gamma = (const float*)d_in[4];
  const float* beta = (const float*)d_in[5];
  float* out = (float*)d_out;

  char* ws = (char*)d_ws;
  bf16x8* wf = (bf16x8*)ws;                      // 32 KB
  float* partials = (float*)(ws + (64 << 10));   // 4096 * 128 * 4 = 2 MB
  float* sstab = (float*)(ws + (64 << 10) + (2 << 20));

  wprep_kernel<<<8, 256, 0, stream>>>(w, wf);
  fused_kernel<0><<<NBLK, 256, 0, stream>>>(z0, z1, wf, cb, nullptr, partials, nullptr);
  bn_finalize_kernel<<<64, 256, 0, stream>>>(partials, gamma, beta, sstab);
  fused_kernel<1><<<NBLK, 256, 0, stream>>>(z0, z1, wf, cb, sstab, partials, out);
}